// Round 8
// baseline (229.014 us; speedup 1.0000x reference)
//
#include <hip/hip_runtime.h>
#include <stdint.h>

#define DCH 64
#define KC 512
#define HWSZ 4096
#define THETA 1e-4f
#define QCODES 128
#define POSB 128

typedef __attribute__((ext_vector_type(8))) short short8v;
typedef __attribute__((ext_vector_type(4))) float floatx4;

// d_ws layout (bytes)
#define WS_WHS   0                        // 512*64 bf16 hi, swizzled rows
#define WS_WLS   65536                    // 512*64 bf16 lo, swizzled rows
#define WS_WNORM 131072                   // 512 f32 (numpy-pairwise exact)
#define WS_CNT   133120                   // int
#define WS_LIST  133184                   // up to 131072 int
#define WS_NEED  (133184 + 131072 * 4)

__device__ __forceinline__ uint16_t f2bf_rne(float x) {
  uint32_t u = __float_as_uint(x);
  uint32_t r = (u + 0x7fffu + ((u >> 16) & 1u)) >> 16;
  return (uint16_t)r;
}
__device__ __forceinline__ float bf2f(uint16_t b) {
  return __uint_as_float(((uint32_t)b) << 16);
}

// numpy pairwise_sum of squares, 64 elems (fp-contract off)
__device__ __forceinline__ float pairwise_sq64(const float* __restrict__ a) {
#pragma clang fp contract(off)
  float r0 = a[0]*a[0], r1 = a[1]*a[1], r2 = a[2]*a[2], r3 = a[3]*a[3];
  float r4 = a[4]*a[4], r5 = a[5]*a[5], r6 = a[6]*a[6], r7 = a[7]*a[7];
#pragma unroll
  for (int i = 8; i < 64; i += 8) {
    r0 += a[i+0]*a[i+0]; r1 += a[i+1]*a[i+1];
    r2 += a[i+2]*a[i+2]; r3 += a[i+3]*a[i+3];
    r4 += a[i+4]*a[i+4]; r5 += a[i+5]*a[i+5];
    r6 += a[i+6]*a[i+6]; r7 += a[i+7]*a[i+7];
  }
  return ((r0+r1)+(r2+r3)) + ((r4+r5)+(r6+r7));
}

// Load 8 Z elements (stride HWSZ), bf16-split element-wise (min live regs).
__device__ __forceinline__ void load_frag(const float* __restrict__ p,
                                          short8v& vh, short8v& vl) {
#pragma unroll
  for (int j = 0; j < 8; ++j) {
    const float v = p[(size_t)j * HWSZ];
    const uint16_t hb = f2bf_rne(v);
    vh[j] = (short)hb;
    vl[j] = (short)f2bf_rne(v - bf2f(hb));
  }
}

// ---------- prep: W -> bf16 split (swizzled image) + exact wnorm ----------
__global__ __launch_bounds__(64) void vq_prep(const float* __restrict__ W,
                                              char* __restrict__ ws) {
  const int c = blockIdx.x * 64 + threadIdx.x;   // 0..511
  const float* __restrict__ wr = W + c * DCH;
  float a[64];
#pragma unroll
  for (int i = 0; i < 16; ++i) {
    const float4 v = ((const float4*)wr)[i];
    a[4*i+0] = v.x; a[4*i+1] = v.y; a[4*i+2] = v.z; a[4*i+3] = v.w;
  }
  ((float*)(ws + WS_WNORM))[c] = pairwise_sq64(a);
  uint16_t* wh = (uint16_t*)(ws + WS_WHS);
  uint16_t* wl = (uint16_t*)(ws + WS_WLS);
#pragma unroll
  for (int gd = 0; gd < 8; ++gd) {
    short8v vh, vl;
#pragma unroll
    for (int e = 0; e < 8; ++e) {
      const float v = a[gd * 8 + e];
      const uint16_t hb = f2bf_rne(v);
      vh[e] = (short)hb;
      vl[e] = (short)f2bf_rne(v - bf2f(hb));
    }
    const int go = (gd ^ (c & 7)) << 3;   // swizzled granule slot
    *(short8v*)(wh + c * DCH + go) = vh;
    *(short8v*)(wl + c * DCH + go) = vl;
  }
  if (c == 0) *(int*)(ws + WS_CNT) = 0;
}

// ---------- main: MFMA scoring + top-2 gap test ----------
// 128 positions/block: 4 waves x 32 pos (two 16-row A-sets), W in LDS quarters.
// __launch_bounds__(256,4): cap VGPR at 128 -> 4 waves/SIMD (R7 was 184/2).
__global__ __launch_bounds__(256, 4) void vq_main(const float* __restrict__ Z,
                                                  char* __restrict__ ws,
                                                  int* __restrict__ out) {
  __shared__ uint16_t wh[QCODES * DCH];   // 16 KB
  __shared__ uint16_t wl[QCODES * DCH];   // 16 KB
  __shared__ float wnlds[KC];             // 2 KB

  const int tid = threadIdx.x;
  const int lane = tid & 63;
  const int wv = tid >> 6;                // 0..3
  const int csub = lane & 15;
  const int gsub = lane >> 4;
  const int nbase = blockIdx.x * POSB;

  const uint16_t* whs = (const uint16_t*)(ws + WS_WHS);
  const uint16_t* wls = (const uint16_t*)(ws + WS_WLS);
  const float* wnorm = (const float*)(ws + WS_WNORM);
  int* cnt = (int*)(ws + WS_CNT);
  int* list = (int*)(ws + WS_LIST);

  // issue quarter-0 W prefetch (pre-swizzled image -> linear copy)
  {
    const char* sh = (const char*)whs;
    const char* sl = (const char*)wls;
#pragma unroll
    for (int r = 0; r < 4; ++r) {
      const int base = wv * 1024 + r * 4096;
      __builtin_amdgcn_global_load_lds((const uint32_t*)(sh + base + lane * 16),
                                       (uint32_t*)((char*)wh + base), 16, 0, 0);
      __builtin_amdgcn_global_load_lds((const uint32_t*)(sl + base + lane * 16),
                                       (uint32_t*)((char*)wl + base), 16, 0, 0);
    }
  }
  // wnorm table -> LDS (broadcast-read later)
  wnlds[tid] = wnorm[tid];
  wnlds[tid + 256] = wnorm[tid + 256];

  // A fragments straight from global, bf16 split in regs (named variables).
  short8v ahA0, ahA1, alA0, alA1, ahB0, ahB1, alB0, alB1;
  {
    const int b = nbase >> 12;
    const int hw0 = nbase & 4095;
    const float* zb = Z + (size_t)b * DCH * HWSZ + hw0 + wv * 32 + csub;
    const int dbase = gsub * 8;
    load_frag(zb + (size_t)(dbase +  0) * HWSZ,      ahA0, alA0);
    load_frag(zb + (size_t)(dbase + 32) * HWSZ,      ahA1, alA1);
    load_frag(zb + (size_t)(dbase +  0) * HWSZ + 16, ahB0, alB0);
    load_frag(zb + (size_t)(dbase + 32) * HWSZ + 16, ahB1, alB1);
  }

  float m1A[4], m2A[4], m1B[4], m2B[4];
  int i1A[4], i1B[4];
#pragma unroll
  for (int r = 0; r < 4; ++r) {
    m1A[r] = 3.4e38f; m2A[r] = 3.4e38f; i1A[r] = 0;
    m1B[r] = 3.4e38f; m2B[r] = 3.4e38f; i1B[r] = 0;
  }

  __syncthreads();  // quarter-0 ready (vmcnt drain + barrier)

#pragma unroll 1
  for (int q = 0; q < 4; ++q) {
#pragma unroll
    for (int t = 0; t < 8; ++t) {
      const int cloc = t * 16 + csub;
      const int kglob = q * QCODES + cloc;
      const float wn = wnlds[kglob];
      const floatx4 zz = {0.f, 0.f, 0.f, 0.f};
      floatx4 accAA, accAB, accBA, accBB;
      // ---- k-chunk 0 (d 0..31): only 2 B-frags live at a time ----
      {
        const int go0 = (gsub ^ (cloc & 7)) << 3;
        const short8v bh0 = *(const short8v*)&wh[cloc * DCH + go0];
        const short8v bl0 = *(const short8v*)&wl[cloc * DCH + go0];
        accAA = __builtin_amdgcn_mfma_f32_16x16x32_bf16(ahA0, bh0, zz, 0, 0, 0);
        accAB = __builtin_amdgcn_mfma_f32_16x16x32_bf16(ahA0, bl0, zz, 0, 0, 0);
        accAB = __builtin_amdgcn_mfma_f32_16x16x32_bf16(alA0, bh0, accAB, 0, 0, 0);
        accBA = __builtin_amdgcn_mfma_f32_16x16x32_bf16(ahB0, bh0, zz, 0, 0, 0);
        accBB = __builtin_amdgcn_mfma_f32_16x16x32_bf16(ahB0, bl0, zz, 0, 0, 0);
        accBB = __builtin_amdgcn_mfma_f32_16x16x32_bf16(alB0, bh0, accBB, 0, 0, 0);
      }
      // ---- k-chunk 1 (d 32..63) ----
      {
        const int go1 = ((4 + gsub) ^ (cloc & 7)) << 3;
        const short8v bh1 = *(const short8v*)&wh[cloc * DCH + go1];
        const short8v bl1 = *(const short8v*)&wl[cloc * DCH + go1];
        accAA = __builtin_amdgcn_mfma_f32_16x16x32_bf16(ahA1, bh1, accAA, 0, 0, 0);
        accAB = __builtin_amdgcn_mfma_f32_16x16x32_bf16(ahA1, bl1, accAB, 0, 0, 0);
        accAB = __builtin_amdgcn_mfma_f32_16x16x32_bf16(alA1, bh1, accAB, 0, 0, 0);
        accBA = __builtin_amdgcn_mfma_f32_16x16x32_bf16(ahB1, bh1, accBA, 0, 0, 0);
        accBB = __builtin_amdgcn_mfma_f32_16x16x32_bf16(ahB1, bl1, accBB, 0, 0, 0);
        accBB = __builtin_amdgcn_mfma_f32_16x16x32_bf16(alB1, bh1, accBB, 0, 0, 0);
      }
#pragma unroll
      for (int r = 0; r < 4; ++r) {
        const float sA = fmaf(-2.0f, accAA[r] + accAB[r], wn);
        i1A[r] = (sA < m1A[r]) ? kglob : i1A[r];
        m2A[r] = fminf(fmaxf(sA, m1A[r]), m2A[r]);
        m1A[r] = fminf(sA, m1A[r]);
        const float sB = fmaf(-2.0f, accBA[r] + accBB[r], wn);
        i1B[r] = (sB < m1B[r]) ? kglob : i1B[r];
        m2B[r] = fminf(fmaxf(sB, m1B[r]), m2B[r]);
        m1B[r] = fminf(sB, m1B[r]);
      }
    }
    if (q < 3) {
      __syncthreads();  // all waves done reading this quarter
      const char* sh = (const char*)(whs + (q + 1) * QCODES * DCH);
      const char* sl = (const char*)(wls + (q + 1) * QCODES * DCH);
#pragma unroll
      for (int r = 0; r < 4; ++r) {
        const int base = wv * 1024 + r * 4096;
        __builtin_amdgcn_global_load_lds((const uint32_t*)(sh + base + lane * 16),
                                         (uint32_t*)((char*)wh + base), 16, 0, 0);
        __builtin_amdgcn_global_load_lds((const uint32_t*)(sl + base + lane * 16),
                                         (uint32_t*)((char*)wl + base), 16, 0, 0);
      }
      __syncthreads();  // next quarter ready
    }
  }

  // top-2 merge across the 16 lanes sharing each row group
#pragma unroll
  for (int off = 1; off < 16; off <<= 1) {
#pragma unroll
    for (int r = 0; r < 4; ++r) {
      {
        const float om1 = __shfl_xor(m1A[r], off, 64);
        const float om2 = __shfl_xor(m2A[r], off, 64);
        const int oi = __shfl_xor(i1A[r], off, 64);
        const float nm2 = fminf(fmaxf(m1A[r], om1), fminf(m2A[r], om2));
        i1A[r] = (om1 < m1A[r]) ? oi : i1A[r];
        m1A[r] = fminf(m1A[r], om1);
        m2A[r] = nm2;
      }
      {
        const float om1 = __shfl_xor(m1B[r], off, 64);
        const float om2 = __shfl_xor(m2B[r], off, 64);
        const int oi = __shfl_xor(i1B[r], off, 64);
        const float nm2 = fminf(fmaxf(m1B[r], om1), fminf(m2B[r], om2));
        i1B[r] = (om1 < m1B[r]) ? oi : i1B[r];
        m1B[r] = fminf(m1B[r], om1);
        m2B[r] = nm2;
      }
    }
  }
  if (csub == 0) {
#pragma unroll
    for (int r = 0; r < 4; ++r) {
      const int posA = nbase + wv * 32 + gsub * 4 + r;
      out[posA] = i1A[r];
      if (!(m2A[r] - m1A[r] > THETA)) {
        const int slot = atomicAdd(cnt, 1);
        list[slot] = posA;
      }
      const int posB = posA + 16;
      out[posB] = i1B[r];
      if (!(m2B[r] - m1B[r] > THETA)) {
        const int slot = atomicAdd(cnt, 1);
        list[slot] = posB;
      }
    }
  }
}

// ---------- rescue: bit-exact numpy re-score of flagged positions ----------
__global__ __launch_bounds__(256) void vq_rescue(const float* __restrict__ Z,
                                                 const float* __restrict__ W,
                                                 char* __restrict__ ws,
                                                 int* __restrict__ out) {
  const int cnt = *(const int*)(ws + WS_CNT);
  if (cnt == 0) return;
  const int* list = (const int*)(ws + WS_LIST);
  const float* wnorm = (const float*)(ws + WS_WNORM);
  const int lane = threadIdx.x & 63;
  const int wvg = blockIdx.x * 4 + (threadIdx.x >> 6);

  for (int j = wvg; j < cnt; j += 256 * 4) {
    const int pos = list[j];
    const int b = pos >> 12, hw = pos & 4095;
    float z[DCH];
    const float* zb = Z + ((size_t)b * DCH) * HWSZ + hw;
#pragma unroll
    for (int d = 0; d < DCH; ++d) z[d] = zb[(size_t)d * HWSZ];
    const float znorm = pairwise_sq64(z);
    float bm = 3.4e38f;
    int bi = 0;
#pragma unroll 1
    for (int j2 = 0; j2 < 8; ++j2) {
      const int k = j2 * 64 + lane;
      const float* wr = W + (size_t)k * DCH;
      float acc = 0.f;
#pragma unroll
      for (int d = 0; d < DCH; ++d) acc = fmaf(z[d], wr[d], acc);
      const float dist = (znorm - 2.0f * acc) + wnorm[k];
      if (dist < bm) { bm = dist; bi = k; }  // ascending k per lane
    }
    // cross-lane argmin, smaller-index-wins on exact ties (numpy rule)
#pragma unroll
    for (int off = 32; off >= 1; off >>= 1) {
      const float ov = __shfl_xor(bm, off, 64);
      const int oi = __shfl_xor(bi, off, 64);
      if (ov < bm || (ov == bm && oi < bi)) { bm = ov; bi = oi; }
    }
    if (lane == 0) out[pos] = bi;
  }
}

// ---------- fallback (R4, known exact) if ws too small ----------
__global__ __launch_bounds__(256, 4) void vq_fallback(const float* __restrict__ Z,
                                                      const float* __restrict__ W,
                                                      int* __restrict__ out) {
  __shared__ float wnorm[KC];
  __shared__ float cmin[4][64];
  __shared__ int cidx[4][64];
  const int tid = threadIdx.x;
  for (int c = tid; c < KC; c += 256) wnorm[c] = pairwise_sq64(W + c * DCH);
  const int lane = tid & 63;
  const int wv = __builtin_amdgcn_readfirstlane(tid >> 6);
  const int n = blockIdx.x * 64 + lane;
  float z[DCH];
  {
    const int b = n >> 12, hw = n & 4095;
    const float* zbase = Z + ((size_t)b * DCH) * HWSZ + hw;
#pragma unroll
    for (int d = 0; d < DCH; ++d) z[d] = zbase[(size_t)d * HWSZ];
  }
  const float znorm = pairwise_sq64(z);
  __syncthreads();
  float bmin = 3.4e38f;
  int bidx = 0;
  const int k0 = wv * 128;
#pragma unroll 1
  for (int kk = 0; kk < 128; kk += 8) {
    const int k = k0 + kk;
    const float* wr = W + (size_t)k * DCH;
    float acc[8];
#pragma unroll
    for (int j = 0; j < 8; ++j) acc[j] = 0.0f;
#pragma unroll
    for (int d = 0; d < DCH; ++d) {
      const float zd = z[d];
#pragma unroll
      for (int j = 0; j < 8; ++j) acc[j] = fmaf(zd, wr[j * DCH + d], acc[j]);
    }
#pragma unroll
    for (int j = 0; j < 8; ++j) {
      const float dist = (znorm - 2.0f * acc[j]) + wnorm[k + j];
      if (dist < bmin) { bmin = dist; bidx = k + j; }
    }
  }
  cmin[wv][lane] = bmin;
  cidx[wv][lane] = bidx;
  __syncthreads();
  if (tid < 64) {
    float m = cmin[0][tid];
    int ix = cidx[0][tid];
#pragma unroll
    for (int h = 1; h < 4; ++h) {
      if (cmin[h][tid] < m) { m = cmin[h][tid]; ix = cidx[h][tid]; }
    }
    out[blockIdx.x * 64 + tid] = ix;
  }
}

extern "C" void kernel_launch(void* const* d_in, const int* in_sizes, int n_in,
                              void* d_out, int out_size, void* d_ws, size_t ws_size,
                              hipStream_t stream) {
  const float* Z = (const float*)d_in[0];
  const float* W = (const float*)d_in[1];
  int* out = (int*)d_out;
  char* ws = (char*)d_ws;
  const int npos = in_sizes[0] / DCH;  // 131072

  if (ws_size < (size_t)WS_NEED) {
    vq_fallback<<<npos / 64, 256, 0, stream>>>(Z, W, out);
    return;
  }
  vq_prep<<<8, 64, 0, stream>>>(W, ws);
  vq_main<<<npos / POSB, 256, 0, stream>>>(Z, ws, out);
  vq_rescue<<<256, 256, 0, stream>>>(Z, W, ws, out);
}

// Round 9
// 144.252 us; speedup vs baseline: 1.5876x; 1.5876x over previous
//
#include <hip/hip_runtime.h>
#include <stdint.h>

#define DCH 64
#define KC 512
#define HWSZ 4096
#define THETA 1e-4f
#define POSB 128

typedef __attribute__((ext_vector_type(8))) short short8v;
typedef __attribute__((ext_vector_type(4))) float floatx4;

// d_ws layout (bytes)
#define WS_WHS   0                        // 512*64 bf16 hi, plain row-major
#define WS_WLS   65536                    // 512*64 bf16 lo, plain row-major
#define WS_WNORM 131072                   // 512 f32 (numpy-pairwise exact)
#define WS_CNT   133120                   // int
#define WS_LIST  133184                   // up to 131072 int
#define WS_NEED  (133184 + 131072 * 4)

__device__ __forceinline__ uint16_t f2bf_rne(float x) {
  uint32_t u = __float_as_uint(x);
  uint32_t r = (u + 0x7fffu + ((u >> 16) & 1u)) >> 16;
  return (uint16_t)r;
}
__device__ __forceinline__ float bf2f(uint16_t b) {
  return __uint_as_float(((uint32_t)b) << 16);
}

// numpy pairwise_sum of squares, 64 elems (fp-contract off)
__device__ __forceinline__ float pairwise_sq64(const float* __restrict__ a) {
#pragma clang fp contract(off)
  float r0 = a[0]*a[0], r1 = a[1]*a[1], r2 = a[2]*a[2], r3 = a[3]*a[3];
  float r4 = a[4]*a[4], r5 = a[5]*a[5], r6 = a[6]*a[6], r7 = a[7]*a[7];
#pragma unroll
  for (int i = 8; i < 64; i += 8) {
    r0 += a[i+0]*a[i+0]; r1 += a[i+1]*a[i+1];
    r2 += a[i+2]*a[i+2]; r3 += a[i+3]*a[i+3];
    r4 += a[i+4]*a[i+4]; r5 += a[i+5]*a[i+5];
    r6 += a[i+6]*a[i+6]; r7 += a[i+7]*a[i+7];
  }
  return ((r0+r1)+(r2+r3)) + ((r4+r5)+(r6+r7));
}

// Load 8 Z elements (stride HWSZ), bf16-split element-wise (min live regs).
__device__ __forceinline__ void load_frag(const float* __restrict__ p,
                                          short8v& vh, short8v& vl) {
#pragma unroll
  for (int j = 0; j < 8; ++j) {
    const float v = p[(size_t)j * HWSZ];
    const uint16_t hb = f2bf_rne(v);
    vh[j] = (short)hb;
    vl[j] = (short)f2bf_rne(v - bf2f(hb));
  }
}

// ---------- prep: W -> bf16 split (plain row-major) + exact wnorm ----------
__global__ __launch_bounds__(64) void vq_prep(const float* __restrict__ W,
                                              char* __restrict__ ws) {
  const int c = blockIdx.x * 64 + threadIdx.x;   // 0..511
  const float* __restrict__ wr = W + c * DCH;
  float a[64];
#pragma unroll
  for (int i = 0; i < 16; ++i) {
    const float4 v = ((const float4*)wr)[i];
    a[4*i+0] = v.x; a[4*i+1] = v.y; a[4*i+2] = v.z; a[4*i+3] = v.w;
  }
  ((float*)(ws + WS_WNORM))[c] = pairwise_sq64(a);
  uint16_t* wh = (uint16_t*)(ws + WS_WHS);
  uint16_t* wl = (uint16_t*)(ws + WS_WLS);
#pragma unroll
  for (int gd = 0; gd < 8; ++gd) {
    short8v vh, vl;
#pragma unroll
    for (int e = 0; e < 8; ++e) {
      const float v = a[gd * 8 + e];
      const uint16_t hb = f2bf_rne(v);
      vh[e] = (short)hb;
      vl[e] = (short)f2bf_rne(v - bf2f(hb));
    }
    *(short8v*)(wh + c * DCH + gd * 8) = vh;
    *(short8v*)(wl + c * DCH + gd * 8) = vl;
  }
  if (c == 0) *(int*)(ws + WS_CNT) = 0;
}

// ---------- main: MFMA scoring + top-2 gap test ----------
// 128 positions/block: 4 waves x 32 pos (two 16-row A-sets).
// NO LDS, NO barriers: the 128 KB split-W image is L1/L2-resident; B-frags
// and wnorm are read straight from global. Waves slip freely.
__global__ __launch_bounds__(256) void vq_main(const float* __restrict__ Z,
                                               char* __restrict__ ws,
                                               int* __restrict__ out) {
  const int tid = threadIdx.x;
  const int lane = tid & 63;
  const int wv = tid >> 6;                // 0..3
  const int csub = lane & 15;
  const int gsub = lane >> 4;
  const int nbase = blockIdx.x * POSB;

  const uint16_t* __restrict__ whs = (const uint16_t*)(ws + WS_WHS);
  const uint16_t* __restrict__ wls = (const uint16_t*)(ws + WS_WLS);
  const float* __restrict__ wnorm = (const float*)(ws + WS_WNORM);
  int* cnt = (int*)(ws + WS_CNT);
  int* list = (int*)(ws + WS_LIST);

  // A fragments straight from global, bf16 split in regs (named variables).
  short8v ahA0, ahA1, alA0, alA1, ahB0, ahB1, alB0, alB1;
  {
    const int b = nbase >> 12;
    const int hw0 = nbase & 4095;
    const float* zb = Z + (size_t)b * DCH * HWSZ + hw0 + wv * 32 + csub;
    const int dbase = gsub * 8;
    load_frag(zb + (size_t)(dbase +  0) * HWSZ,      ahA0, alA0);
    load_frag(zb + (size_t)(dbase + 32) * HWSZ,      ahA1, alA1);
    load_frag(zb + (size_t)(dbase +  0) * HWSZ + 16, ahB0, alB0);
    load_frag(zb + (size_t)(dbase + 32) * HWSZ + 16, ahB1, alB1);
  }

  float m1A[4], m2A[4], m1B[4], m2B[4];
  int i1A[4], i1B[4];
#pragma unroll
  for (int r = 0; r < 4; ++r) {
    m1A[r] = 3.4e38f; m2A[r] = 3.4e38f; i1A[r] = 0;
    m1B[r] = 3.4e38f; m2B[r] = 3.4e38f; i1B[r] = 0;
  }

  // 32 tiles x 16 codes, straight from the global image.
#pragma unroll 2
  for (int kt = 0; kt < KC / 16; ++kt) {
    const int cloc = kt * 16 + csub;        // global code index
    const float wn = wnorm[cloc];
    const uint16_t* wrh = whs + cloc * DCH + gsub * 8;
    const uint16_t* wrl = wls + cloc * DCH + gsub * 8;
    const short8v bh0 = *(const short8v*)(wrh);
    const short8v bh1 = *(const short8v*)(wrh + 32);
    const short8v bl0 = *(const short8v*)(wrl);
    const short8v bl1 = *(const short8v*)(wrl + 32);
    const floatx4 zz = {0.f, 0.f, 0.f, 0.f};
    // one 6-MFMA chain per position-set; sets A/B are independent (ILP=2)
    floatx4 accA = __builtin_amdgcn_mfma_f32_16x16x32_bf16(ahA0, bh0, zz, 0, 0, 0);
    floatx4 accB = __builtin_amdgcn_mfma_f32_16x16x32_bf16(ahB0, bh0, zz, 0, 0, 0);
    accA = __builtin_amdgcn_mfma_f32_16x16x32_bf16(ahA1, bh1, accA, 0, 0, 0);
    accB = __builtin_amdgcn_mfma_f32_16x16x32_bf16(ahB1, bh1, accB, 0, 0, 0);
    accA = __builtin_amdgcn_mfma_f32_16x16x32_bf16(ahA0, bl0, accA, 0, 0, 0);
    accB = __builtin_amdgcn_mfma_f32_16x16x32_bf16(ahB0, bl0, accB, 0, 0, 0);
    accA = __builtin_amdgcn_mfma_f32_16x16x32_bf16(ahA1, bl1, accA, 0, 0, 0);
    accB = __builtin_amdgcn_mfma_f32_16x16x32_bf16(ahB1, bl1, accB, 0, 0, 0);
    accA = __builtin_amdgcn_mfma_f32_16x16x32_bf16(alA0, bh0, accA, 0, 0, 0);
    accB = __builtin_amdgcn_mfma_f32_16x16x32_bf16(alB0, bh0, accB, 0, 0, 0);
    accA = __builtin_amdgcn_mfma_f32_16x16x32_bf16(alA1, bh1, accA, 0, 0, 0);
    accB = __builtin_amdgcn_mfma_f32_16x16x32_bf16(alB1, bh1, accB, 0, 0, 0);
#pragma unroll
    for (int r = 0; r < 4; ++r) {
      const float sA = fmaf(-2.0f, accA[r], wn);
      i1A[r] = (sA < m1A[r]) ? cloc : i1A[r];
      m2A[r] = fminf(fmaxf(sA, m1A[r]), m2A[r]);
      m1A[r] = fminf(sA, m1A[r]);
      const float sB = fmaf(-2.0f, accB[r], wn);
      i1B[r] = (sB < m1B[r]) ? cloc : i1B[r];
      m2B[r] = fminf(fmaxf(sB, m1B[r]), m2B[r]);
      m1B[r] = fminf(sB, m1B[r]);
    }
  }

  // top-2 merge across the 16 lanes sharing each row group
#pragma unroll
  for (int off = 1; off < 16; off <<= 1) {
#pragma unroll
    for (int r = 0; r < 4; ++r) {
      {
        const float om1 = __shfl_xor(m1A[r], off, 64);
        const float om2 = __shfl_xor(m2A[r], off, 64);
        const int oi = __shfl_xor(i1A[r], off, 64);
        const float nm2 = fminf(fmaxf(m1A[r], om1), fminf(m2A[r], om2));
        i1A[r] = (om1 < m1A[r]) ? oi : i1A[r];
        m1A[r] = fminf(m1A[r], om1);
        m2A[r] = nm2;
      }
      {
        const float om1 = __shfl_xor(m1B[r], off, 64);
        const float om2 = __shfl_xor(m2B[r], off, 64);
        const int oi = __shfl_xor(i1B[r], off, 64);
        const float nm2 = fminf(fmaxf(m1B[r], om1), fminf(m2B[r], om2));
        i1B[r] = (om1 < m1B[r]) ? oi : i1B[r];
        m1B[r] = fminf(m1B[r], om1);
        m2B[r] = nm2;
      }
    }
  }
  if (csub == 0) {
#pragma unroll
    for (int r = 0; r < 4; ++r) {
      const int posA = nbase + wv * 32 + gsub * 4 + r;
      out[posA] = i1A[r];
      if (!(m2A[r] - m1A[r] > THETA)) {
        const int slot = atomicAdd(cnt, 1);
        list[slot] = posA;
      }
      const int posB = posA + 16;
      out[posB] = i1B[r];
      if (!(m2B[r] - m1B[r] > THETA)) {
        const int slot = atomicAdd(cnt, 1);
        list[slot] = posB;
      }
    }
  }
}

// ---------- rescue: bit-exact numpy re-score of flagged positions ----------
__global__ __launch_bounds__(256) void vq_rescue(const float* __restrict__ Z,
                                                 const float* __restrict__ W,
                                                 char* __restrict__ ws,
                                                 int* __restrict__ out) {
  const int cnt = *(const int*)(ws + WS_CNT);
  if (cnt == 0) return;
  const int* list = (const int*)(ws + WS_LIST);
  const float* wnorm = (const float*)(ws + WS_WNORM);
  const int lane = threadIdx.x & 63;
  const int wvg = blockIdx.x * 4 + (threadIdx.x >> 6);

  for (int j = wvg; j < cnt; j += 256 * 4) {
    const int pos = list[j];
    const int b = pos >> 12, hw = pos & 4095;
    float z[DCH];
    const float* zb = Z + ((size_t)b * DCH) * HWSZ + hw;
#pragma unroll
    for (int d = 0; d < DCH; ++d) z[d] = zb[(size_t)d * HWSZ];
    const float znorm = pairwise_sq64(z);
    float bm = 3.4e38f;
    int bi = 0;
#pragma unroll 1
    for (int j2 = 0; j2 < 8; ++j2) {
      const int k = j2 * 64 + lane;
      const float* wr = W + (size_t)k * DCH;
      float acc = 0.f;
#pragma unroll
      for (int d = 0; d < DCH; ++d) acc = fmaf(z[d], wr[d], acc);
      const float dist = (znorm - 2.0f * acc) + wnorm[k];
      if (dist < bm) { bm = dist; bi = k; }  // ascending k per lane
    }
    // cross-lane argmin, smaller-index-wins on exact ties (numpy rule)
#pragma unroll
    for (int off = 32; off >= 1; off >>= 1) {
      const float ov = __shfl_xor(bm, off, 64);
      const int oi = __shfl_xor(bi, off, 64);
      if (ov < bm || (ov == bm && oi < bi)) { bm = ov; bi = oi; }
    }
    if (lane == 0) out[pos] = bi;
  }
}

// ---------- fallback (R4, known exact) if ws too small ----------
__global__ __launch_bounds__(256, 4) void vq_fallback(const float* __restrict__ Z,
                                                      const float* __restrict__ W,
                                                      int* __restrict__ out) {
  __shared__ float wnorm[KC];
  __shared__ float cmin[4][64];
  __shared__ int cidx[4][64];
  const int tid = threadIdx.x;
  for (int c = tid; c < KC; c += 256) wnorm[c] = pairwise_sq64(W + c * DCH);
  const int lane = tid & 63;
  const int wv = __builtin_amdgcn_readfirstlane(tid >> 6);
  const int n = blockIdx.x * 64 + lane;
  float z[DCH];
  {
    const int b = n >> 12, hw = n & 4095;
    const float* zbase = Z + ((size_t)b * DCH) * HWSZ + hw;
#pragma unroll
    for (int d = 0; d < DCH; ++d) z[d] = zbase[(size_t)d * HWSZ];
  }
  const float znorm = pairwise_sq64(z);
  __syncthreads();
  float bmin = 3.4e38f;
  int bidx = 0;
  const int k0 = wv * 128;
#pragma unroll 1
  for (int kk = 0; kk < 128; kk += 8) {
    const int k = k0 + kk;
    const float* wr = W + (size_t)k * DCH;
    float acc[8];
#pragma unroll
    for (int j = 0; j < 8; ++j) acc[j] = 0.0f;
#pragma unroll
    for (int d = 0; d < DCH; ++d) {
      const float zd = z[d];
#pragma unroll
      for (int j = 0; j < 8; ++j) acc[j] = fmaf(zd, wr[j * DCH + d], acc[j]);
    }
#pragma unroll
    for (int j = 0; j < 8; ++j) {
      const float dist = (znorm - 2.0f * acc[j]) + wnorm[k + j];
      if (dist < bmin) { bmin = dist; bidx = k + j; }
    }
  }
  cmin[wv][lane] = bmin;
  cidx[wv][lane] = bidx;
  __syncthreads();
  if (tid < 64) {
    float m = cmin[0][tid];
    int ix = cidx[0][tid];
#pragma unroll
    for (int h = 1; h < 4; ++h) {
      if (cmin[h][tid] < m) { m = cmin[h][tid]; ix = cidx[h][tid]; }
    }
    out[blockIdx.x * 64 + tid] = ix;
  }
}

extern "C" void kernel_launch(void* const* d_in, const int* in_sizes, int n_in,
                              void* d_out, int out_size, void* d_ws, size_t ws_size,
                              hipStream_t stream) {
  const float* Z = (const float*)d_in[0];
  const float* W = (const float*)d_in[1];
  int* out = (int*)d_out;
  char* ws = (char*)d_ws;
  const int npos = in_sizes[0] / DCH;  // 131072

  if (ws_size < (size_t)WS_NEED) {
    vq_fallback<<<npos / 64, 256, 0, stream>>>(Z, W, out);
    return;
  }
  vq_prep<<<8, 64, 0, stream>>>(W, ws);
  vq_main<<<npos / POSB, 256, 0, stream>>>(Z, ws, out);
  vq_rescue<<<256, 256, 0, stream>>>(Z, W, ws, out);
}

// Round 10
// 99.593 us; speedup vs baseline: 2.2995x; 1.4484x over previous
//
#include <hip/hip_runtime.h>
#include <stdint.h>

#define DCH 64
#define KC 512
#define HWSZ 4096
#define THETA 1e-4f
#define POSB 512      // positions per block (16 waves x 32)
#define BLOCK 1024

typedef __attribute__((ext_vector_type(8))) short short8v;
typedef __attribute__((ext_vector_type(4))) float floatx4;

// d_ws layout (bytes)
#define WS_WHS   0                        // 512*64 bf16 hi, SWIZZLED rows
#define WS_WLS   65536                    // 512*64 bf16 lo, SWIZZLED rows (contiguous after hi)
#define WS_WNORM 131072                   // 512 f32 (numpy-pairwise exact)
#define WS_CNT   133120                   // int
#define WS_LIST  133184                   // up to 131072 int
#define WS_NEED  (133184 + 131072 * 4)

__device__ __forceinline__ uint16_t f2bf_rne(float x) {
  uint32_t u = __float_as_uint(x);
  uint32_t r = (u + 0x7fffu + ((u >> 16) & 1u)) >> 16;
  return (uint16_t)r;
}
__device__ __forceinline__ float bf2f(uint16_t b) {
  return __uint_as_float(((uint32_t)b) << 16);
}

// numpy pairwise_sum of squares, 64 elems (fp-contract off)
__device__ __forceinline__ float pairwise_sq64(const float* __restrict__ a) {
#pragma clang fp contract(off)
  float r0 = a[0]*a[0], r1 = a[1]*a[1], r2 = a[2]*a[2], r3 = a[3]*a[3];
  float r4 = a[4]*a[4], r5 = a[5]*a[5], r6 = a[6]*a[6], r7 = a[7]*a[7];
#pragma unroll
  for (int i = 8; i < 64; i += 8) {
    r0 += a[i+0]*a[i+0]; r1 += a[i+1]*a[i+1];
    r2 += a[i+2]*a[i+2]; r3 += a[i+3]*a[i+3];
    r4 += a[i+4]*a[i+4]; r5 += a[i+5]*a[i+5];
    r6 += a[i+6]*a[i+6]; r7 += a[i+7]*a[i+7];
  }
  return ((r0+r1)+(r2+r3)) + ((r4+r5)+(r6+r7));
}

// Load 8 Z elements (stride HWSZ), bf16-split element-wise (min live regs).
__device__ __forceinline__ void load_frag(const float* __restrict__ p,
                                          short8v& vh, short8v& vl) {
#pragma unroll
  for (int j = 0; j < 8; ++j) {
    const float v = p[(size_t)j * HWSZ];
    const uint16_t hb = f2bf_rne(v);
    vh[j] = (short)hb;
    vl[j] = (short)f2bf_rne(v - bf2f(hb));
  }
}

// ---------- prep: W -> bf16 split (SWIZZLED image) + exact wnorm ----------
__global__ __launch_bounds__(64) void vq_prep(const float* __restrict__ W,
                                              char* __restrict__ ws) {
  const int c = blockIdx.x * 64 + threadIdx.x;   // 0..511
  const float* __restrict__ wr = W + c * DCH;
  float a[64];
#pragma unroll
  for (int i = 0; i < 16; ++i) {
    const float4 v = ((const float4*)wr)[i];
    a[4*i+0] = v.x; a[4*i+1] = v.y; a[4*i+2] = v.z; a[4*i+3] = v.w;
  }
  ((float*)(ws + WS_WNORM))[c] = pairwise_sq64(a);
  uint16_t* wh = (uint16_t*)(ws + WS_WHS);
  uint16_t* wl = (uint16_t*)(ws + WS_WLS);
#pragma unroll
  for (int gd = 0; gd < 8; ++gd) {
    short8v vh, vl;
#pragma unroll
    for (int e = 0; e < 8; ++e) {
      const float v = a[gd * 8 + e];
      const uint16_t hb = f2bf_rne(v);
      vh[e] = (short)hb;
      vl[e] = (short)f2bf_rne(v - bf2f(hb));
    }
    const int go = (gd ^ (c & 7)) << 3;   // swizzled granule slot
    *(short8v*)(wh + c * DCH + go) = vh;
    *(short8v*)(wl + c * DCH + go) = vl;
  }
  if (c == 0) *(int*)(ws + WS_CNT) = 0;
}

// ---------- main: MFMA scoring + top-2 gap test ----------
// 1024 threads = 16 waves x 32 positions = 512 pos/block; grid = 256 = 1/CU.
// Whole 128 KB split-W image + wnorm staged in LDS ONCE, single barrier,
// then a barrier-free ds_read->MFMA loop.
__global__ __launch_bounds__(BLOCK) void vq_main(const float* __restrict__ Z,
                                                 char* __restrict__ ws,
                                                 int* __restrict__ out) {
  __shared__ uint16_t img[65536];   // 128 KB: hi [0,32768), lo [32768,65536)
  __shared__ float wnlds[KC];       // 2 KB

  const int tid = threadIdx.x;
  const int lane = tid & 63;
  const int wv = tid >> 6;                // 0..15
  const int csub = lane & 15;
  const int gsub = lane >> 4;
  const int nbase = blockIdx.x * POSB;

  const char* __restrict__ img_src = (const char*)ws;  // WS_WHS=0, 128 KB contiguous
  const float* __restrict__ wnorm = (const float*)(ws + WS_WNORM);
  int* cnt = (int*)(ws + WS_CNT);
  int* list = (int*)(ws + WS_LIST);

  // ---- stage the full image: 8 rounds x 16 KB (linear copy; image is
  //      pre-swizzled so LDS dest stays linear per global_load_lds rules) ----
#pragma unroll
  for (int r = 0; r < 8; ++r) {
    const int base = r * 16384 + wv * 1024;   // wave-uniform LDS/byte base
    __builtin_amdgcn_global_load_lds((const uint32_t*)(img_src + base + lane * 16),
                                     (uint32_t*)((char*)img + base), 16, 0, 0);
  }
  // wnorm (2 KB) via waves 0-1 (wave-uniform predicate: splits at wave boundary)
  if (tid < 128) {
    const int base = wv * 1024;
    __builtin_amdgcn_global_load_lds((const uint32_t*)((const char*)wnorm + base + lane * 16),
                                     (uint32_t*)((char*)wnlds + base), 16, 0, 0);
  }

  // A fragments straight from global, bf16 split in regs (named variables).
  short8v ahA0, ahA1, alA0, alA1, ahB0, ahB1, alB0, alB1;
  {
    const int b = nbase >> 12;
    const int hw0 = nbase & 4095;
    const float* zb = Z + (size_t)b * DCH * HWSZ + hw0 + wv * 32 + csub;
    const int dbase = gsub * 8;
    load_frag(zb + (size_t)(dbase +  0) * HWSZ,      ahA0, alA0);
    load_frag(zb + (size_t)(dbase + 32) * HWSZ,      ahA1, alA1);
    load_frag(zb + (size_t)(dbase +  0) * HWSZ + 16, ahB0, alB0);
    load_frag(zb + (size_t)(dbase + 32) * HWSZ + 16, ahB1, alB1);
  }

  float m1A[4], m2A[4], m1B[4], m2B[4];
  int i1A[4], i1B[4];
#pragma unroll
  for (int r = 0; r < 4; ++r) {
    m1A[r] = 3.4e38f; m2A[r] = 3.4e38f; i1A[r] = 0;
    m1B[r] = 3.4e38f; m2B[r] = 3.4e38f; i1B[r] = 0;
  }

  __syncthreads();  // image + wnorm ready (vmcnt drained); ONLY barrier.

  const uint16_t* __restrict__ whl = img;            // hi
  const uint16_t* __restrict__ wll = img + 32768;    // lo

  // 32 tiles x 16 codes from LDS (swizzled), barrier-free.
#pragma unroll 4
  for (int kt = 0; kt < KC / 16; ++kt) {
    const int cloc = kt * 16 + csub;        // global code index
    const float wn = wnlds[cloc];
    const int go0 = (gsub ^ (cloc & 7)) << 3;
    const int go1 = ((4 + gsub) ^ (cloc & 7)) << 3;
    const short8v bh0 = *(const short8v*)&whl[cloc * DCH + go0];
    const short8v bh1 = *(const short8v*)&whl[cloc * DCH + go1];
    const short8v bl0 = *(const short8v*)&wll[cloc * DCH + go0];
    const short8v bl1 = *(const short8v*)&wll[cloc * DCH + go1];
    const floatx4 zz = {0.f, 0.f, 0.f, 0.f};
    // one 6-MFMA chain per position-set; sets A/B independent (ILP=2)
    floatx4 accA = __builtin_amdgcn_mfma_f32_16x16x32_bf16(ahA0, bh0, zz, 0, 0, 0);
    floatx4 accB = __builtin_amdgcn_mfma_f32_16x16x32_bf16(ahB0, bh0, zz, 0, 0, 0);
    accA = __builtin_amdgcn_mfma_f32_16x16x32_bf16(ahA1, bh1, accA, 0, 0, 0);
    accB = __builtin_amdgcn_mfma_f32_16x16x32_bf16(ahB1, bh1, accB, 0, 0, 0);
    accA = __builtin_amdgcn_mfma_f32_16x16x32_bf16(ahA0, bl0, accA, 0, 0, 0);
    accB = __builtin_amdgcn_mfma_f32_16x16x32_bf16(ahB0, bl0, accB, 0, 0, 0);
    accA = __builtin_amdgcn_mfma_f32_16x16x32_bf16(ahA1, bl1, accA, 0, 0, 0);
    accB = __builtin_amdgcn_mfma_f32_16x16x32_bf16(ahB1, bl1, accB, 0, 0, 0);
    accA = __builtin_amdgcn_mfma_f32_16x16x32_bf16(alA0, bh0, accA, 0, 0, 0);
    accB = __builtin_amdgcn_mfma_f32_16x16x32_bf16(alB0, bh0, accB, 0, 0, 0);
    accA = __builtin_amdgcn_mfma_f32_16x16x32_bf16(alA1, bh1, accA, 0, 0, 0);
    accB = __builtin_amdgcn_mfma_f32_16x16x32_bf16(alB1, bh1, accB, 0, 0, 0);
#pragma unroll
    for (int r = 0; r < 4; ++r) {
      const float sA = fmaf(-2.0f, accA[r], wn);
      i1A[r] = (sA < m1A[r]) ? cloc : i1A[r];
      m2A[r] = fminf(fmaxf(sA, m1A[r]), m2A[r]);
      m1A[r] = fminf(sA, m1A[r]);
      const float sB = fmaf(-2.0f, accB[r], wn);
      i1B[r] = (sB < m1B[r]) ? cloc : i1B[r];
      m2B[r] = fminf(fmaxf(sB, m1B[r]), m2B[r]);
      m1B[r] = fminf(sB, m1B[r]);
    }
  }

  // top-2 merge across the 16 lanes sharing each row group
#pragma unroll
  for (int off = 1; off < 16; off <<= 1) {
#pragma unroll
    for (int r = 0; r < 4; ++r) {
      {
        const float om1 = __shfl_xor(m1A[r], off, 64);
        const float om2 = __shfl_xor(m2A[r], off, 64);
        const int oi = __shfl_xor(i1A[r], off, 64);
        const float nm2 = fminf(fmaxf(m1A[r], om1), fminf(m2A[r], om2));
        i1A[r] = (om1 < m1A[r]) ? oi : i1A[r];
        m1A[r] = fminf(m1A[r], om1);
        m2A[r] = nm2;
      }
      {
        const float om1 = __shfl_xor(m1B[r], off, 64);
        const float om2 = __shfl_xor(m2B[r], off, 64);
        const int oi = __shfl_xor(i1B[r], off, 64);
        const float nm2 = fminf(fmaxf(m1B[r], om1), fminf(m2B[r], om2));
        i1B[r] = (om1 < m1B[r]) ? oi : i1B[r];
        m1B[r] = fminf(m1B[r], om1);
        m2B[r] = nm2;
      }
    }
  }
  if (csub == 0) {
#pragma unroll
    for (int r = 0; r < 4; ++r) {
      const int posA = nbase + wv * 32 + gsub * 4 + r;
      out[posA] = i1A[r];
      if (!(m2A[r] - m1A[r] > THETA)) {
        const int slot = atomicAdd(cnt, 1);
        list[slot] = posA;
      }
      const int posB = posA + 16;
      out[posB] = i1B[r];
      if (!(m2B[r] - m1B[r] > THETA)) {
        const int slot = atomicAdd(cnt, 1);
        list[slot] = posB;
      }
    }
  }
}

// ---------- rescue: bit-exact numpy re-score of flagged positions ----------
__global__ __launch_bounds__(256) void vq_rescue(const float* __restrict__ Z,
                                                 const float* __restrict__ W,
                                                 char* __restrict__ ws,
                                                 int* __restrict__ out) {
  const int cnt = *(const int*)(ws + WS_CNT);
  if (cnt == 0) return;
  const int* list = (const int*)(ws + WS_LIST);
  const float* wnorm = (const float*)(ws + WS_WNORM);
  const int lane = threadIdx.x & 63;
  const int wvg = blockIdx.x * 4 + (threadIdx.x >> 6);

  for (int j = wvg; j < cnt; j += 256 * 4) {
    const int pos = list[j];
    const int b = pos >> 12, hw = pos & 4095;
    float z[DCH];
    const float* zb = Z + ((size_t)b * DCH) * HWSZ + hw;
#pragma unroll
    for (int d = 0; d < DCH; ++d) z[d] = zb[(size_t)d * HWSZ];
    const float znorm = pairwise_sq64(z);
    float bm = 3.4e38f;
    int bi = 0;
#pragma unroll 1
    for (int j2 = 0; j2 < 8; ++j2) {
      const int k = j2 * 64 + lane;
      const float* wr = W + (size_t)k * DCH;
      float acc = 0.f;
#pragma unroll
      for (int d = 0; d < DCH; ++d) acc = fmaf(z[d], wr[d], acc);
      const float dist = (znorm - 2.0f * acc) + wnorm[k];
      if (dist < bm) { bm = dist; bi = k; }  // ascending k per lane
    }
    // cross-lane argmin, smaller-index-wins on exact ties (numpy rule)
#pragma unroll
    for (int off = 32; off >= 1; off >>= 1) {
      const float ov = __shfl_xor(bm, off, 64);
      const int oi = __shfl_xor(bi, off, 64);
      if (ov < bm || (ov == bm && oi < bi)) { bm = ov; bi = oi; }
    }
    if (lane == 0) out[pos] = bi;
  }
}

// ---------- fallback (R4, known exact) if ws too small ----------
__global__ __launch_bounds__(256, 4) void vq_fallback(const float* __restrict__ Z,
                                                      const float* __restrict__ W,
                                                      int* __restrict__ out) {
  __shared__ float wnorm[KC];
  __shared__ float cmin[4][64];
  __shared__ int cidx[4][64];
  const int tid = threadIdx.x;
  for (int c = tid; c < KC; c += 256) wnorm[c] = pairwise_sq64(W + c * DCH);
  const int lane = tid & 63;
  const int wv = __builtin_amdgcn_readfirstlane(tid >> 6);
  const int n = blockIdx.x * 64 + lane;
  float z[DCH];
  {
    const int b = n >> 12, hw = n & 4095;
    const float* zbase = Z + ((size_t)b * DCH) * HWSZ + hw;
#pragma unroll
    for (int d = 0; d < DCH; ++d) z[d] = zbase[(size_t)d * HWSZ];
  }
  const float znorm = pairwise_sq64(z);
  __syncthreads();
  float bmin = 3.4e38f;
  int bidx = 0;
  const int k0 = wv * 128;
#pragma unroll 1
  for (int kk = 0; kk < 128; kk += 8) {
    const int k = k0 + kk;
    const float* wr = W + (size_t)k * DCH;
    float acc[8];
#pragma unroll
    for (int j = 0; j < 8; ++j) acc[j] = 0.0f;
#pragma unroll
    for (int d = 0; d < DCH; ++d) {
      const float zd = z[d];
#pragma unroll
      for (int j = 0; j < 8; ++j) acc[j] = fmaf(zd, wr[j * DCH + d], acc[j]);
    }
#pragma unroll
    for (int j = 0; j < 8; ++j) {
      const float dist = (znorm - 2.0f * acc[j]) + wnorm[k + j];
      if (dist < bmin) { bmin = dist; bidx = k + j; }
    }
  }
  cmin[wv][lane] = bmin;
  cidx[wv][lane] = bidx;
  __syncthreads();
  if (tid < 64) {
    float m = cmin[0][tid];
    int ix = cidx[0][tid];
#pragma unroll
    for (int h = 1; h < 4; ++h) {
      if (cmin[h][tid] < m) { m = cmin[h][tid]; ix = cidx[h][tid]; }
    }
    out[blockIdx.x * 64 + tid] = ix;
  }
}

extern "C" void kernel_launch(void* const* d_in, const int* in_sizes, int n_in,
                              void* d_out, int out_size, void* d_ws, size_t ws_size,
                              hipStream_t stream) {
  const float* Z = (const float*)d_in[0];
  const float* W = (const float*)d_in[1];
  int* out = (int*)d_out;
  char* ws = (char*)d_ws;
  const int npos = in_sizes[0] / DCH;  // 131072

  if (ws_size < (size_t)WS_NEED) {
    vq_fallback<<<npos / 64, 256, 0, stream>>>(Z, W, out);
    return;
  }
  vq_prep<<<8, 64, 0, stream>>>(W, ws);
  vq_main<<<npos / POSB, BLOCK, 0, stream>>>(Z, ws, out);
  vq_rescue<<<256, 256, 0, stream>>>(Z, W, ws, out);
}

// Round 11
// 69.812 us; speedup vs baseline: 3.2804x; 1.4266x over previous
//
#include <hip/hip_runtime.h>
#include <stdint.h>

#define DCH 64
#define KC 512
#define HWSZ 4096
#define THETA 1e-4f
#define POSB 512      // positions per block (16 waves x 32)
#define BLOCK 1024
#define PADW 65       // rescue LDS row stride (floats): bank=(row+d)%32, conflict-free

typedef __attribute__((ext_vector_type(8))) short short8v;
typedef __attribute__((ext_vector_type(4))) float floatx4;

// d_ws layout (bytes)
#define WS_WHS   0                        // 512*64 bf16 hi, SWIZZLED rows
#define WS_WLS   65536                    // 512*64 bf16 lo, SWIZZLED rows
#define WS_WNORM 131072                   // 512 f32 (numpy-pairwise exact)
#define WS_CNT   133120                   // int
#define WS_LIST  133184                   // up to 131072 int
#define WS_NEED  (133184 + 131072 * 4)

__device__ __forceinline__ uint16_t f2bf_rne(float x) {
  uint32_t u = __float_as_uint(x);
  uint32_t r = (u + 0x7fffu + ((u >> 16) & 1u)) >> 16;
  return (uint16_t)r;
}
__device__ __forceinline__ float bf2f(uint16_t b) {
  return __uint_as_float(((uint32_t)b) << 16);
}

// numpy pairwise_sum of squares, 64 elems (fp-contract off)
__device__ __forceinline__ float pairwise_sq64(const float* __restrict__ a) {
#pragma clang fp contract(off)
  float r0 = a[0]*a[0], r1 = a[1]*a[1], r2 = a[2]*a[2], r3 = a[3]*a[3];
  float r4 = a[4]*a[4], r5 = a[5]*a[5], r6 = a[6]*a[6], r7 = a[7]*a[7];
#pragma unroll
  for (int i = 8; i < 64; i += 8) {
    r0 += a[i+0]*a[i+0]; r1 += a[i+1]*a[i+1];
    r2 += a[i+2]*a[i+2]; r3 += a[i+3]*a[i+3];
    r4 += a[i+4]*a[i+4]; r5 += a[i+5]*a[i+5];
    r6 += a[i+6]*a[i+6]; r7 += a[i+7]*a[i+7];
  }
  return ((r0+r1)+(r2+r3)) + ((r4+r5)+(r6+r7));
}

// Load 8 Z elements (stride HWSZ), bf16-split element-wise (min live regs).
__device__ __forceinline__ void load_frag(const float* __restrict__ p,
                                          short8v& vh, short8v& vl) {
#pragma unroll
  for (int j = 0; j < 8; ++j) {
    const float v = p[(size_t)j * HWSZ];
    const uint16_t hb = f2bf_rne(v);
    vh[j] = (short)hb;
    vl[j] = (short)f2bf_rne(v - bf2f(hb));
  }
}

// ---------- prep: W -> bf16 split (SWIZZLED image) + exact wnorm ----------
__global__ __launch_bounds__(64) void vq_prep(const float* __restrict__ W,
                                              char* __restrict__ ws) {
  const int c = blockIdx.x * 64 + threadIdx.x;   // 0..511
  const float* __restrict__ wr = W + c * DCH;
  float a[64];
#pragma unroll
  for (int i = 0; i < 16; ++i) {
    const float4 v = ((const float4*)wr)[i];
    a[4*i+0] = v.x; a[4*i+1] = v.y; a[4*i+2] = v.z; a[4*i+3] = v.w;
  }
  ((float*)(ws + WS_WNORM))[c] = pairwise_sq64(a);
  uint16_t* wh = (uint16_t*)(ws + WS_WHS);
  uint16_t* wl = (uint16_t*)(ws + WS_WLS);
#pragma unroll
  for (int gd = 0; gd < 8; ++gd) {
    short8v vh, vl;
#pragma unroll
    for (int e = 0; e < 8; ++e) {
      const float v = a[gd * 8 + e];
      const uint16_t hb = f2bf_rne(v);
      vh[e] = (short)hb;
      vl[e] = (short)f2bf_rne(v - bf2f(hb));
    }
    const int go = (gd ^ (c & 7)) << 3;   // swizzled granule slot
    *(short8v*)(wh + c * DCH + go) = vh;
    *(short8v*)(wl + c * DCH + go) = vl;
  }
  if (c == 0) *(int*)(ws + WS_CNT) = 0;
}

// ---------- main: MFMA scoring + top-2 gap test (R10 structure, unchanged) ----------
__global__ __launch_bounds__(BLOCK) void vq_main(const float* __restrict__ Z,
                                                 char* __restrict__ ws,
                                                 int* __restrict__ out) {
  __shared__ uint16_t img[65536];   // 128 KB: hi [0,32768), lo [32768,65536)
  __shared__ float wnlds[KC];       // 2 KB

  const int tid = threadIdx.x;
  const int lane = tid & 63;
  const int wv = tid >> 6;                // 0..15
  const int csub = lane & 15;
  const int gsub = lane >> 4;
  const int nbase = blockIdx.x * POSB;

  const char* __restrict__ img_src = (const char*)ws;  // 128 KB contiguous
  const float* __restrict__ wnorm = (const float*)(ws + WS_WNORM);
  int* cnt = (int*)(ws + WS_CNT);
  int* list = (int*)(ws + WS_LIST);

#pragma unroll
  for (int r = 0; r < 8; ++r) {
    const int base = r * 16384 + wv * 1024;   // wave-uniform LDS byte base
    __builtin_amdgcn_global_load_lds((const uint32_t*)(img_src + base + lane * 16),
                                     (uint32_t*)((char*)img + base), 16, 0, 0);
  }
  if (tid < 128) {
    const int base = wv * 1024;
    __builtin_amdgcn_global_load_lds((const uint32_t*)((const char*)wnorm + base + lane * 16),
                                     (uint32_t*)((char*)wnlds + base), 16, 0, 0);
  }

  short8v ahA0, ahA1, alA0, alA1, ahB0, ahB1, alB0, alB1;
  {
    const int b = nbase >> 12;
    const int hw0 = nbase & 4095;
    const float* zb = Z + (size_t)b * DCH * HWSZ + hw0 + wv * 32 + csub;
    const int dbase = gsub * 8;
    load_frag(zb + (size_t)(dbase +  0) * HWSZ,      ahA0, alA0);
    load_frag(zb + (size_t)(dbase + 32) * HWSZ,      ahA1, alA1);
    load_frag(zb + (size_t)(dbase +  0) * HWSZ + 16, ahB0, alB0);
    load_frag(zb + (size_t)(dbase + 32) * HWSZ + 16, ahB1, alB1);
  }

  float m1A[4], m2A[4], m1B[4], m2B[4];
  int i1A[4], i1B[4];
#pragma unroll
  for (int r = 0; r < 4; ++r) {
    m1A[r] = 3.4e38f; m2A[r] = 3.4e38f; i1A[r] = 0;
    m1B[r] = 3.4e38f; m2B[r] = 3.4e38f; i1B[r] = 0;
  }

  __syncthreads();  // image + wnorm ready; ONLY barrier.

  const uint16_t* __restrict__ whl = img;            // hi
  const uint16_t* __restrict__ wll = img + 32768;    // lo

#pragma unroll 4
  for (int kt = 0; kt < KC / 16; ++kt) {
    const int cloc = kt * 16 + csub;
    const float wn = wnlds[cloc];
    const int go0 = (gsub ^ (cloc & 7)) << 3;
    const int go1 = ((4 + gsub) ^ (cloc & 7)) << 3;
    const short8v bh0 = *(const short8v*)&whl[cloc * DCH + go0];
    const short8v bh1 = *(const short8v*)&whl[cloc * DCH + go1];
    const short8v bl0 = *(const short8v*)&wll[cloc * DCH + go0];
    const short8v bl1 = *(const short8v*)&wll[cloc * DCH + go1];
    const floatx4 zz = {0.f, 0.f, 0.f, 0.f};
    floatx4 accA = __builtin_amdgcn_mfma_f32_16x16x32_bf16(ahA0, bh0, zz, 0, 0, 0);
    floatx4 accB = __builtin_amdgcn_mfma_f32_16x16x32_bf16(ahB0, bh0, zz, 0, 0, 0);
    accA = __builtin_amdgcn_mfma_f32_16x16x32_bf16(ahA1, bh1, accA, 0, 0, 0);
    accB = __builtin_amdgcn_mfma_f32_16x16x32_bf16(ahB1, bh1, accB, 0, 0, 0);
    accA = __builtin_amdgcn_mfma_f32_16x16x32_bf16(ahA0, bl0, accA, 0, 0, 0);
    accB = __builtin_amdgcn_mfma_f32_16x16x32_bf16(ahB0, bl0, accB, 0, 0, 0);
    accA = __builtin_amdgcn_mfma_f32_16x16x32_bf16(ahA1, bl1, accA, 0, 0, 0);
    accB = __builtin_amdgcn_mfma_f32_16x16x32_bf16(ahB1, bl1, accB, 0, 0, 0);
    accA = __builtin_amdgcn_mfma_f32_16x16x32_bf16(alA0, bh0, accA, 0, 0, 0);
    accB = __builtin_amdgcn_mfma_f32_16x16x32_bf16(alB0, bh0, accB, 0, 0, 0);
    accA = __builtin_amdgcn_mfma_f32_16x16x32_bf16(alA1, bh1, accA, 0, 0, 0);
    accB = __builtin_amdgcn_mfma_f32_16x16x32_bf16(alB1, bh1, accB, 0, 0, 0);
#pragma unroll
    for (int r = 0; r < 4; ++r) {
      const float sA = fmaf(-2.0f, accA[r], wn);
      i1A[r] = (sA < m1A[r]) ? cloc : i1A[r];
      m2A[r] = fminf(fmaxf(sA, m1A[r]), m2A[r]);
      m1A[r] = fminf(sA, m1A[r]);
      const float sB = fmaf(-2.0f, accB[r], wn);
      i1B[r] = (sB < m1B[r]) ? cloc : i1B[r];
      m2B[r] = fminf(fmaxf(sB, m1B[r]), m2B[r]);
      m1B[r] = fminf(sB, m1B[r]);
    }
  }

#pragma unroll
  for (int off = 1; off < 16; off <<= 1) {
#pragma unroll
    for (int r = 0; r < 4; ++r) {
      {
        const float om1 = __shfl_xor(m1A[r], off, 64);
        const float om2 = __shfl_xor(m2A[r], off, 64);
        const int oi = __shfl_xor(i1A[r], off, 64);
        const float nm2 = fminf(fmaxf(m1A[r], om1), fminf(m2A[r], om2));
        i1A[r] = (om1 < m1A[r]) ? oi : i1A[r];
        m1A[r] = fminf(m1A[r], om1);
        m2A[r] = nm2;
      }
      {
        const float om1 = __shfl_xor(m1B[r], off, 64);
        const float om2 = __shfl_xor(m2B[r], off, 64);
        const int oi = __shfl_xor(i1B[r], off, 64);
        const float nm2 = fminf(fmaxf(m1B[r], om1), fminf(m2B[r], om2));
        i1B[r] = (om1 < m1B[r]) ? oi : i1B[r];
        m1B[r] = fminf(m1B[r], om1);
        m2B[r] = nm2;
      }
    }
  }
  if (csub == 0) {
#pragma unroll
    for (int r = 0; r < 4; ++r) {
      const int posA = nbase + wv * 32 + gsub * 4 + r;
      out[posA] = i1A[r];
      if (!(m2A[r] - m1A[r] > THETA)) {
        const int slot = atomicAdd(cnt, 1);
        list[slot] = posA;
      }
      const int posB = posA + 16;
      out[posB] = i1B[r];
      if (!(m2B[r] - m1B[r] > THETA)) {
        const int slot = atomicAdd(cnt, 1);
        list[slot] = posB;
      }
    }
  }
}

// ---------- rescue v2: LDS-staged W, conflict-free; bit-exact numpy order ----------
__global__ __launch_bounds__(256) void vq_rescue(const float* __restrict__ Z,
                                                 const float* __restrict__ W,
                                                 char* __restrict__ ws,
                                                 int* __restrict__ out) {
  __shared__ float wt[KC * PADW];   // 512 x 65 floats = 133,120 B
  const int cnt = *(const int*)(ws + WS_CNT);
  if (blockIdx.x * 4 >= cnt) return;   // block-uniform early out (before staging)

  const int lane = threadIdx.x & 63;
  const int wv = threadIdx.x >> 6;     // 0..3
  const int wvg = blockIdx.x * 4 + wv;
  const int* list = (const int*)(ws + WS_LIST);
  const float* wnorm = (const float*)(ws + WS_WNORM);

  // stage W (fp32, bit-exact copy) with padded rows:
  // global read coalesced (256B/row); LDS write bank=(c+lane)%32 conflict-free.
  for (int c = wv; c < KC; c += 4) {
    wt[c * PADW + lane] = W[c * DCH + lane];
  }
  __syncthreads();

  for (int j = wvg; j < cnt; j += 256 * 4) {
    const int pos = list[j];
    const int b = pos >> 12, hw = pos & 4095;
    float z[DCH];
    const float* zb = Z + ((size_t)b * DCH) * HWSZ + hw;
#pragma unroll
    for (int d = 0; d < DCH; ++d) z[d] = zb[(size_t)d * HWSZ];
    const float znorm = pairwise_sq64(z);
    float bm = 3.4e38f;
    int bi = 0;
#pragma unroll 1
    for (int j2 = 0; j2 < 8; ++j2) {
      const int k = j2 * 64 + lane;
      const float* __restrict__ wrow = &wt[k * PADW];  // lane-own row, conflict-free
      float acc = 0.f;
#pragma unroll
      for (int d = 0; d < DCH; ++d) acc = fmaf(z[d], wrow[d], acc);
      const float dist = (znorm - 2.0f * acc) + wnorm[k];
      if (dist < bm) { bm = dist; bi = k; }  // ascending k per lane
    }
    // cross-lane argmin, smaller-index-wins on exact ties (numpy rule)
#pragma unroll
    for (int off = 32; off >= 1; off >>= 1) {
      const float ov = __shfl_xor(bm, off, 64);
      const int oi = __shfl_xor(bi, off, 64);
      if (ov < bm || (ov == bm && oi < bi)) { bm = ov; bi = oi; }
    }
    if (lane == 0) out[pos] = bi;
  }
}

// ---------- fallback (R4, known exact) if ws too small ----------
__global__ __launch_bounds__(256, 4) void vq_fallback(const float* __restrict__ Z,
                                                      const float* __restrict__ W,
                                                      int* __restrict__ out) {
  __shared__ float wnorm[KC];
  __shared__ float cmin[4][64];
  __shared__ int cidx[4][64];
  const int tid = threadIdx.x;
  for (int c = tid; c < KC; c += 256) wnorm[c] = pairwise_sq64(W + c * DCH);
  const int lane = tid & 63;
  const int wv = __builtin_amdgcn_readfirstlane(tid >> 6);
  const int n = blockIdx.x * 64 + lane;
  float z[DCH];
  {
    const int b = n >> 12, hw = n & 4095;
    const float* zbase = Z + ((size_t)b * DCH) * HWSZ + hw;
#pragma unroll
    for (int d = 0; d < DCH; ++d) z[d] = zbase[(size_t)d * HWSZ];
  }
  const float znorm = pairwise_sq64(z);
  __syncthreads();
  float bmin = 3.4e38f;
  int bidx = 0;
  const int k0 = wv * 128;
#pragma unroll 1
  for (int kk = 0; kk < 128; kk += 8) {
    const int k = k0 + kk;
    const float* wr = W + (size_t)k * DCH;
    float acc[8];
#pragma unroll
    for (int j = 0; j < 8; ++j) acc[j] = 0.0f;
#pragma unroll
    for (int d = 0; d < DCH; ++d) {
      const float zd = z[d];
#pragma unroll
      for (int j = 0; j < 8; ++j) acc[j] = fmaf(zd, wr[j * DCH + d], acc[j]);
    }
#pragma unroll
    for (int j = 0; j < 8; ++j) {
      const float dist = (znorm - 2.0f * acc[j]) + wnorm[k + j];
      if (dist < bmin) { bmin = dist; bidx = k + j; }
    }
  }
  cmin[wv][lane] = bmin;
  cidx[wv][lane] = bidx;
  __syncthreads();
  if (tid < 64) {
    float m = cmin[0][tid];
    int ix = cidx[0][tid];
#pragma unroll
    for (int h = 1; h < 4; ++h) {
      if (cmin[h][tid] < m) { m = cmin[h][tid]; ix = cidx[h][tid]; }
    }
    out[blockIdx.x * 64 + tid] = ix;
  }
}

extern "C" void kernel_launch(void* const* d_in, const int* in_sizes, int n_in,
                              void* d_out, int out_size, void* d_ws, size_t ws_size,
                              hipStream_t stream) {
  const float* Z = (const float*)d_in[0];
  const float* W = (const float*)d_in[1];
  int* out = (int*)d_out;
  char* ws = (char*)d_ws;
  const int npos = in_sizes[0] / DCH;  // 131072

  if (ws_size < (size_t)WS_NEED) {
    vq_fallback<<<npos / 64, 256, 0, stream>>>(Z, W, out);
    return;
  }
  vq_prep<<<8, 64, 0, stream>>>(W, ws);
  vq_main<<<npos / POSB, BLOCK, 0, stream>>>(Z, ws, out);
  vq_rescue<<<256, 256, 0, stream>>>(Z, W, ws, out);
}

// Round 12
// 69.708 us; speedup vs baseline: 3.2853x; 1.0015x over previous
//
#include <hip/hip_runtime.h>
#include <stdint.h>

#define DCH 64
#define KC 512
#define HWSZ 4096
#define THETA 1e-4f
#define POSB 512      // positions per block (16 waves x 32)
#define BLOCK 1024
#define PADW 65       // rescue LDS row stride (floats): bank=(row+d)%32, conflict-free

typedef __attribute__((ext_vector_type(8))) short short8v;
typedef __attribute__((ext_vector_type(4))) float floatx4;

// d_ws layout (bytes)
#define WS_WHS   0                        // 512*64 bf16 hi, SWIZZLED rows
#define WS_WLS   65536                    // 512*64 bf16 lo, SWIZZLED rows
#define WS_WNORM 131072                   // 512 f32 (numpy-pairwise exact)
#define WS_CNT   133120                   // int
#define WS_LIST  133184                   // up to 131072 int
#define WS_NEED  (133184 + 131072 * 4)

__device__ __forceinline__ uint16_t f2bf_rne(float x) {
  uint32_t u = __float_as_uint(x);
  uint32_t r = (u + 0x7fffu + ((u >> 16) & 1u)) >> 16;
  return (uint16_t)r;
}
__device__ __forceinline__ float bf2f(uint16_t b) {
  return __uint_as_float(((uint32_t)b) << 16);
}

// numpy pairwise_sum of squares, 64 elems (fp-contract off)
__device__ __forceinline__ float pairwise_sq64(const float* __restrict__ a) {
#pragma clang fp contract(off)
  float r0 = a[0]*a[0], r1 = a[1]*a[1], r2 = a[2]*a[2], r3 = a[3]*a[3];
  float r4 = a[4]*a[4], r5 = a[5]*a[5], r6 = a[6]*a[6], r7 = a[7]*a[7];
#pragma unroll
  for (int i = 8; i < 64; i += 8) {
    r0 += a[i+0]*a[i+0]; r1 += a[i+1]*a[i+1];
    r2 += a[i+2]*a[i+2]; r3 += a[i+3]*a[i+3];
    r4 += a[i+4]*a[i+4]; r5 += a[i+5]*a[i+5];
    r6 += a[i+6]*a[i+6]; r7 += a[i+7]*a[i+7];
  }
  return ((r0+r1)+(r2+r3)) + ((r4+r5)+(r6+r7));
}

// Load 8 Z elements (stride HWSZ), bf16-split element-wise (min live regs).
__device__ __forceinline__ void load_frag(const float* __restrict__ p,
                                          short8v& vh, short8v& vl) {
#pragma unroll
  for (int j = 0; j < 8; ++j) {
    const float v = p[(size_t)j * HWSZ];
    const uint16_t hb = f2bf_rne(v);
    vh[j] = (short)hb;
    vl[j] = (short)f2bf_rne(v - bf2f(hb));
  }
}

// ---------- prep: W -> bf16 split (SWIZZLED image) + exact wnorm ----------
__global__ __launch_bounds__(64) void vq_prep(const float* __restrict__ W,
                                              char* __restrict__ ws) {
  const int c = blockIdx.x * 64 + threadIdx.x;   // 0..511
  const float* __restrict__ wr = W + c * DCH;
  float a[64];
#pragma unroll
  for (int i = 0; i < 16; ++i) {
    const float4 v = ((const float4*)wr)[i];
    a[4*i+0] = v.x; a[4*i+1] = v.y; a[4*i+2] = v.z; a[4*i+3] = v.w;
  }
  ((float*)(ws + WS_WNORM))[c] = pairwise_sq64(a);
  uint16_t* wh = (uint16_t*)(ws + WS_WHS);
  uint16_t* wl = (uint16_t*)(ws + WS_WLS);
#pragma unroll
  for (int gd = 0; gd < 8; ++gd) {
    short8v vh, vl;
#pragma unroll
    for (int e = 0; e < 8; ++e) {
      const float v = a[gd * 8 + e];
      const uint16_t hb = f2bf_rne(v);
      vh[e] = (short)hb;
      vl[e] = (short)f2bf_rne(v - bf2f(hb));
    }
    const int go = (gd ^ (c & 7)) << 3;   // swizzled granule slot
    *(short8v*)(wh + c * DCH + go) = vh;
    *(short8v*)(wl + c * DCH + go) = vl;
  }
  if (c == 0) *(int*)(ws + WS_CNT) = 0;
}

// ---------- main: MFMA scoring + top-2 gap test ----------
// 1024 threads = 16 waves x 32 positions; grid = 256 = 1 block/CU.
// Whole 128 KB split-W image in LDS once, single barrier, barrier-free loop.
// R12: 3 independent 2-deep MFMA chains per position-set (12 streams/wave).
__global__ __launch_bounds__(BLOCK) void vq_main(const float* __restrict__ Z,
                                                 char* __restrict__ ws,
                                                 int* __restrict__ out) {
  __shared__ uint16_t img[65536];   // 128 KB: hi [0,32768), lo [32768,65536)
  __shared__ float wnlds[KC];       // 2 KB

  const int tid = threadIdx.x;
  const int lane = tid & 63;
  const int wv = tid >> 6;                // 0..15
  const int csub = lane & 15;
  const int gsub = lane >> 4;
  const int nbase = blockIdx.x * POSB;

  const char* __restrict__ img_src = (const char*)ws;  // 128 KB contiguous
  const float* __restrict__ wnorm = (const float*)(ws + WS_WNORM);
  int* cnt = (int*)(ws + WS_CNT);
  int* list = (int*)(ws + WS_LIST);

#pragma unroll
  for (int r = 0; r < 8; ++r) {
    const int base = r * 16384 + wv * 1024;   // wave-uniform LDS byte base
    __builtin_amdgcn_global_load_lds((const uint32_t*)(img_src + base + lane * 16),
                                     (uint32_t*)((char*)img + base), 16, 0, 0);
  }
  if (tid < 128) {
    const int base = wv * 1024;
    __builtin_amdgcn_global_load_lds((const uint32_t*)((const char*)wnorm + base + lane * 16),
                                     (uint32_t*)((char*)wnlds + base), 16, 0, 0);
  }

  short8v ahA0, ahA1, alA0, alA1, ahB0, ahB1, alB0, alB1;
  {
    const int b = nbase >> 12;
    const int hw0 = nbase & 4095;
    const float* zb = Z + (size_t)b * DCH * HWSZ + hw0 + wv * 32 + csub;
    const int dbase = gsub * 8;
    load_frag(zb + (size_t)(dbase +  0) * HWSZ,      ahA0, alA0);
    load_frag(zb + (size_t)(dbase + 32) * HWSZ,      ahA1, alA1);
    load_frag(zb + (size_t)(dbase +  0) * HWSZ + 16, ahB0, alB0);
    load_frag(zb + (size_t)(dbase + 32) * HWSZ + 16, ahB1, alB1);
  }

  float m1A[4], m2A[4], m1B[4], m2B[4];
  int i1A[4], i1B[4];
#pragma unroll
  for (int r = 0; r < 4; ++r) {
    m1A[r] = 3.4e38f; m2A[r] = 3.4e38f; i1A[r] = 0;
    m1B[r] = 3.4e38f; m2B[r] = 3.4e38f; i1B[r] = 0;
  }

  __syncthreads();  // image + wnorm ready; ONLY barrier.

  const uint16_t* __restrict__ whl = img;            // hi
  const uint16_t* __restrict__ wll = img + 32768;    // lo

  // loop-invariant swizzle slots (cloc&7 == csub&7 since kt*16 % 8 == 0)
  const int go0 = (gsub ^ (csub & 7)) << 3;
  const int go1 = ((4 + gsub) ^ (csub & 7)) << 3;

#pragma unroll 8
  for (int kt = 0; kt < KC / 16; ++kt) {
    const int cloc = kt * 16 + csub;
    const float wn = wnlds[cloc];
    const short8v bh0 = *(const short8v*)&whl[cloc * DCH + go0];
    const short8v bh1 = *(const short8v*)&whl[cloc * DCH + go1];
    const short8v bl0 = *(const short8v*)&wll[cloc * DCH + go0];
    const short8v bl1 = *(const short8v*)&wll[cloc * DCH + go1];
    const floatx4 zz = {0.f, 0.f, 0.f, 0.f};
    // 3 independent 2-deep chains per set (hh, h*lo, lo*h) -> 6 streams here,
    // 12+ in flight with unroll. Dep latency hidden without barriers.
    floatx4 cA1 = __builtin_amdgcn_mfma_f32_16x16x32_bf16(ahA0, bh0, zz, 0, 0, 0);
    floatx4 cB1 = __builtin_amdgcn_mfma_f32_16x16x32_bf16(ahB0, bh0, zz, 0, 0, 0);
    floatx4 cA2 = __builtin_amdgcn_mfma_f32_16x16x32_bf16(ahA0, bl0, zz, 0, 0, 0);
    floatx4 cB2 = __builtin_amdgcn_mfma_f32_16x16x32_bf16(ahB0, bl0, zz, 0, 0, 0);
    floatx4 cA3 = __builtin_amdgcn_mfma_f32_16x16x32_bf16(alA0, bh0, zz, 0, 0, 0);
    floatx4 cB3 = __builtin_amdgcn_mfma_f32_16x16x32_bf16(alB0, bh0, zz, 0, 0, 0);
    cA1 = __builtin_amdgcn_mfma_f32_16x16x32_bf16(ahA1, bh1, cA1, 0, 0, 0);
    cB1 = __builtin_amdgcn_mfma_f32_16x16x32_bf16(ahB1, bh1, cB1, 0, 0, 0);
    cA2 = __builtin_amdgcn_mfma_f32_16x16x32_bf16(ahA1, bl1, cA2, 0, 0, 0);
    cB2 = __builtin_amdgcn_mfma_f32_16x16x32_bf16(ahB1, bl1, cB2, 0, 0, 0);
    cA3 = __builtin_amdgcn_mfma_f32_16x16x32_bf16(alA1, bh1, cA3, 0, 0, 0);
    cB3 = __builtin_amdgcn_mfma_f32_16x16x32_bf16(alB1, bh1, cB3, 0, 0, 0);
#pragma unroll
    for (int r = 0; r < 4; ++r) {
      const float sA = fmaf(-2.0f, (cA1[r] + cA2[r]) + cA3[r], wn);
      i1A[r] = (sA < m1A[r]) ? cloc : i1A[r];
      m2A[r] = fminf(fmaxf(sA, m1A[r]), m2A[r]);
      m1A[r] = fminf(sA, m1A[r]);
      const float sB = fmaf(-2.0f, (cB1[r] + cB2[r]) + cB3[r], wn);
      i1B[r] = (sB < m1B[r]) ? cloc : i1B[r];
      m2B[r] = fminf(fmaxf(sB, m1B[r]), m2B[r]);
      m1B[r] = fminf(sB, m1B[r]);
    }
  }

#pragma unroll
  for (int off = 1; off < 16; off <<= 1) {
#pragma unroll
    for (int r = 0; r < 4; ++r) {
      {
        const float om1 = __shfl_xor(m1A[r], off, 64);
        const float om2 = __shfl_xor(m2A[r], off, 64);
        const int oi = __shfl_xor(i1A[r], off, 64);
        const float nm2 = fminf(fmaxf(m1A[r], om1), fminf(m2A[r], om2));
        i1A[r] = (om1 < m1A[r]) ? oi : i1A[r];
        m1A[r] = fminf(m1A[r], om1);
        m2A[r] = nm2;
      }
      {
        const float om1 = __shfl_xor(m1B[r], off, 64);
        const float om2 = __shfl_xor(m2B[r], off, 64);
        const int oi = __shfl_xor(i1B[r], off, 64);
        const float nm2 = fminf(fmaxf(m1B[r], om1), fminf(m2B[r], om2));
        i1B[r] = (om1 < m1B[r]) ? oi : i1B[r];
        m1B[r] = fminf(m1B[r], om1);
        m2B[r] = nm2;
      }
    }
  }
  if (csub == 0) {
#pragma unroll
    for (int r = 0; r < 4; ++r) {
      const int posA = nbase + wv * 32 + gsub * 4 + r;
      out[posA] = i1A[r];
      if (!(m2A[r] - m1A[r] > THETA)) {
        const int slot = atomicAdd(cnt, 1);
        list[slot] = posA;
      }
      const int posB = posA + 16;
      out[posB] = i1B[r];
      if (!(m2B[r] - m1B[r] > THETA)) {
        const int slot = atomicAdd(cnt, 1);
        list[slot] = posB;
      }
    }
  }
}

// ---------- rescue: LDS-staged W, conflict-free; bit-exact numpy order ----------
__global__ __launch_bounds__(256) void vq_rescue(const float* __restrict__ Z,
                                                 const float* __restrict__ W,
                                                 char* __restrict__ ws,
                                                 int* __restrict__ out) {
  __shared__ float wt[KC * PADW];   // 512 x 65 floats = 133,120 B
  const int cnt = *(const int*)(ws + WS_CNT);
  if (blockIdx.x * 4 >= cnt) return;   // block-uniform early out (before staging)

  const int lane = threadIdx.x & 63;
  const int wv = threadIdx.x >> 6;     // 0..3
  const int wvg = blockIdx.x * 4 + wv;
  const int* list = (const int*)(ws + WS_LIST);
  const float* wnorm = (const float*)(ws + WS_WNORM);

  for (int c = wv; c < KC; c += 4) {
    wt[c * PADW + lane] = W[c * DCH + lane];
  }
  __syncthreads();

  for (int j = wvg; j < cnt; j += 256 * 4) {
    const int pos = list[j];
    const int b = pos >> 12, hw = pos & 4095;
    float z[DCH];
    const float* zb = Z + ((size_t)b * DCH) * HWSZ + hw;
#pragma unroll
    for (int d = 0; d < DCH; ++d) z[d] = zb[(size_t)d * HWSZ];
    const float znorm = pairwise_sq64(z);
    float bm = 3.4e38f;
    int bi = 0;
#pragma unroll 1
    for (int j2 = 0; j2 < 8; ++j2) {
      const int k = j2 * 64 + lane;
      const float* __restrict__ wrow = &wt[k * PADW];  // lane-own row, conflict-free
      float acc = 0.f;
#pragma unroll
      for (int d = 0; d < DCH; ++d) acc = fmaf(z[d], wrow[d], acc);
      const float dist = (znorm - 2.0f * acc) + wnorm[k];
      if (dist < bm) { bm = dist; bi = k; }  // ascending k per lane
    }
#pragma unroll
    for (int off = 32; off >= 1; off >>= 1) {
      const float ov = __shfl_xor(bm, off, 64);
      const int oi = __shfl_xor(bi, off, 64);
      if (ov < bm || (ov == bm && oi < bi)) { bm = ov; bi = oi; }
    }
    if (lane == 0) out[pos] = bi;
  }
}

// ---------- fallback (R4, known exact) if ws too small ----------
__global__ __launch_bounds__(256, 4) void vq_fallback(const float* __restrict__ Z,
                                                      const float* __restrict__ W,
                                                      int* __restrict__ out) {
  __shared__ float wnorm[KC];
  __shared__ float cmin[4][64];
  __shared__ int cidx[4][64];
  const int tid = threadIdx.x;
  for (int c = tid; c < KC; c += 256) wnorm[c] = pairwise_sq64(W + c * DCH);
  const int lane = tid & 63;
  const int wv = __builtin_amdgcn_readfirstlane(tid >> 6);
  const int n = blockIdx.x * 64 + lane;
  float z[DCH];
  {
    const int b = n >> 12, hw = n & 4095;
    const float* zbase = Z + ((size_t)b * DCH) * HWSZ + hw;
#pragma unroll
    for (int d = 0; d < DCH; ++d) z[d] = zbase[(size_t)d * HWSZ];
  }
  const float znorm = pairwise_sq64(z);
  __syncthreads();
  float bmin = 3.4e38f;
  int bidx = 0;
  const int k0 = wv * 128;
#pragma unroll 1
  for (int kk = 0; kk < 128; kk += 8) {
    const int k = k0 + kk;
    const float* wr = W + (size_t)k * DCH;
    float acc[8];
#pragma unroll
    for (int j = 0; j < 8; ++j) acc[j] = 0.0f;
#pragma unroll
    for (int d = 0; d < DCH; ++d) {
      const float zd = z[d];
#pragma unroll
      for (int j = 0; j < 8; ++j) acc[j] = fmaf(zd, wr[j * DCH + d], acc[j]);
    }
#pragma unroll
    for (int j = 0; j < 8; ++j) {
      const float dist = (znorm - 2.0f * acc[j]) + wnorm[k + j];
      if (dist < bmin) { bmin = dist; bidx = k + j; }
    }
  }
  cmin[wv][lane] = bmin;
  cidx[wv][lane] = bidx;
  __syncthreads();
  if (tid < 64) {
    float m = cmin[0][tid];
    int ix = cidx[0][tid];
#pragma unroll
    for (int h = 1; h < 4; ++h) {
      if (cmin[h][tid] < m) { m = cmin[h][tid]; ix = cidx[h][tid]; }
    }
    out[blockIdx.x * 64 + tid] = ix;
  }
}

extern "C" void kernel_launch(void* const* d_in, const int* in_sizes, int n_in,
                              void* d_out, int out_size, void* d_ws, size_t ws_size,
                              hipStream_t stream) {
  const float* Z = (const float*)d_in[0];
  const float* W = (const float*)d_in[1];
  int* out = (int*)d_out;
  char* ws = (char*)d_ws;
  const int npos = in_sizes[0] / DCH;  // 131072

  if (ws_size < (size_t)WS_NEED) {
    vq_fallback<<<npos / 64, 256, 0, stream>>>(Z, W, out);
    return;
  }
  vq_prep<<<8, 64, 0, stream>>>(W, ws);
  vq_main<<<npos / POSB, BLOCK, 0, stream>>>(Z, ws, out);
  vq_rescue<<<256, 256, 0, stream>>>(Z, W, ws, out);
}